// Round 1
// baseline (534.566 us; speedup 1.0000x reference)
//
#include <hip/hip_runtime.h>
#include <stdint.h>

#define S_LEN 2048
#define B_SZ  4
#define E_SZ  1024
#define H_CNT 16
#define D_HD  64
#define M_ROWS (S_LEN * B_SZ)   // 8192

typedef __attribute__((ext_vector_type(4))) float          f32x4;
typedef __attribute__((ext_vector_type(8))) __bf16         bf16x8;
typedef __attribute__((ext_vector_type(4))) unsigned short u16x4;
typedef __attribute__((ext_vector_type(4))) int            i32x4;

__device__ __forceinline__ unsigned short f2bf(float f) {
    union { float f; unsigned u; } v; v.f = f;
    unsigned r = v.u + 0x7fffu + ((v.u >> 16) & 1u);
    return (unsigned short)(r >> 16);
}

#define MFMA(a, b, c) __builtin_amdgcn_mfma_f32_16x16x32_bf16((a), (b), (c), 0, 0, 0)

// ---------------- weight fp32 -> bf16 ----------------
__global__ __launch_bounds__(256)
void convert_f32_bf16(const float* __restrict__ src, unsigned short* __restrict__ dst, int n4) {
    int i = blockIdx.x * 256 + threadIdx.x;
    if (i < n4) {
        f32x4 v = ((const f32x4*)src)[i];
        u16x4 o;
        o.x = f2bf(v.x); o.y = f2bf(v.y); o.z = f2bf(v.z); o.w = f2bf(v.w);
        ((u16x4*)dst)[i] = o;
    }
}

// ---------------- projection GEMM: C = A * W^T + b ----------------
// A: [M=8192, K=1024]   (fp32 input activations, or bf16 ctx)
// W: [N=1024, K=1024]   bf16 (row-major, K contiguous -> B^T GEMM layout)
// OUT_QKV: write bf16 to [B,H,S,D];  else write fp32 to [M, N] (= [S,B,E])
template<bool SRC_F32, bool OUT_QKV>
__global__ __launch_bounds__(256)
void proj_gemm(const void* __restrict__ Ap,
               const unsigned short* __restrict__ Bw,
               const float* __restrict__ bias,
               void* __restrict__ Outp)
{
    __shared__ unsigned short Al[128][40];   // +8 pad: bank-conflict-free b128 reads
    __shared__ unsigned short Bl[128][40];

    const int t    = threadIdx.x;
    const int lane = t & 63;
    const int wave = t >> 6;
    const int bm   = (blockIdx.x >> 3) << 7;   // 64 m-tiles
    const int bn   = (blockIdx.x & 7) << 7;    // 8 n-tiles
    const int wr   = (wave >> 1) << 6;
    const int wc   = (wave & 1) << 6;
    const int lrow = lane & 15;
    const int lk   = lane >> 4;

    f32x4 acc[4][4];
    #pragma unroll
    for (int i = 0; i < 4; ++i)
        #pragma unroll
        for (int j = 0; j < 4; ++j) acc[i][j] = (f32x4)0.0f;

    for (int k0 = 0; k0 < E_SZ; k0 += 32) {
        __syncthreads();
        if (SRC_F32) {
            const float* A = (const float*)Ap;
            const int r = t >> 3;
            const int c = (t & 7) << 2;
            #pragma unroll
            for (int j = 0; j < 4; ++j) {
                f32x4 v = *(const f32x4*)(A + (size_t)(bm + r + j*32) * E_SZ + k0 + c);
                u16x4 o;
                o.x = f2bf(v.x); o.y = f2bf(v.y); o.z = f2bf(v.z); o.w = f2bf(v.w);
                *(u16x4*)(&Al[r + j*32][c]) = o;
            }
        } else {
            const unsigned short* A = (const unsigned short*)Ap;
            const int r = t >> 2;
            const int c = (t & 3) << 3;
            #pragma unroll
            for (int j = 0; j < 2; ++j) {
                i32x4 v = *(const i32x4*)(A + (size_t)(bm + r + j*64) * E_SZ + k0 + c);
                *(i32x4*)(&Al[r + j*64][c]) = v;
            }
        }
        {
            const int r = t >> 2;
            const int c = (t & 3) << 3;
            #pragma unroll
            for (int j = 0; j < 2; ++j) {
                i32x4 v = *(const i32x4*)(Bw + (size_t)(bn + r + j*64) * E_SZ + k0 + c);
                *(i32x4*)(&Bl[r + j*64][c]) = v;
            }
        }
        __syncthreads();

        bf16x8 af[4], bfr[4];
        #pragma unroll
        for (int i = 0; i < 4; ++i) af[i]  = *(const bf16x8*)(&Al[wr + i*16 + lrow][lk*8]);
        #pragma unroll
        for (int i = 0; i < 4; ++i) bfr[i] = *(const bf16x8*)(&Bl[wc + i*16 + lrow][lk*8]);
        #pragma unroll
        for (int i = 0; i < 4; ++i)
            #pragma unroll
            for (int j = 0; j < 4; ++j)
                acc[i][j] = MFMA(af[i], bfr[j], acc[i][j]);
    }

    const int crow = lk << 2;
    #pragma unroll
    for (int i = 0; i < 4; ++i) {
        #pragma unroll
        for (int j = 0; j < 4; ++j) {
            const int n = bn + wc + j*16 + lrow;
            const float bv = bias[n];
            #pragma unroll
            for (int r = 0; r < 4; ++r) {
                const int m = bm + wr + i*16 + crow + r;
                const float val = acc[i][j][r] + bv;
                if (OUT_QKV) {
                    const int s = m >> 2, b = m & 3;       // m = s*B + b
                    const int h = n >> 6, d = n & 63;      // n = h*D + d
                    ((unsigned short*)Outp)[((size_t)(b*H_CNT + h)*S_LEN + s)*D_HD + d] = f2bf(val);
                } else {
                    ((float*)Outp)[(size_t)m * E_SZ + n] = val;
                }
            }
        }
    }
}

// ---------------- flash attention fwd (causal), saves m,l ----------------
// grid: B*H*(S/128); block 256 (4 waves x 32 q-rows); kv tiles of 64
__global__ __launch_bounds__(256)
void flash_fwd(const unsigned short* __restrict__ Qb,
               const unsigned short* __restrict__ Kb,
               const unsigned short* __restrict__ Vb,
               unsigned short* __restrict__ ctx,
               float* __restrict__ mout,
               float* __restrict__ lout)
{
    __shared__ unsigned short Kl[64][72];
    __shared__ unsigned short Vt[64][72];   // V transposed: [d][kv]
    __shared__ unsigned short Pl[4][32][72];

    const int t    = threadIdx.x;
    const int lane = t & 63, wave = t >> 6;
    const int lrow = lane & 15, lk = lane >> 4;
    const int qt   = blockIdx.x & (S_LEN/128 - 1);
    const int bh   = blockIdx.x >> 4;
    const int b    = bh >> 4, h = bh & 15;

    const size_t base = (size_t)bh * S_LEN * D_HD;
    const unsigned short* Q = Qb + base;
    const unsigned short* K = Kb + base;
    const unsigned short* V = Vb + base;

    const int qbase = qt*128 + wave*32;

    bf16x8 qf[2][2];
    #pragma unroll
    for (int mf = 0; mf < 2; ++mf)
        #pragma unroll
        for (int ks = 0; ks < 2; ++ks)
            qf[mf][ks] = *(const bf16x8*)(Q + (size_t)(qbase + mf*16 + lrow)*D_HD + ks*32 + lk*8);

    f32x4 ctxa[2][4];
    float mst[2][4], lst[2][4];
    #pragma unroll
    for (int mf = 0; mf < 2; ++mf) {
        #pragma unroll
        for (int nf = 0; nf < 4; ++nf) ctxa[mf][nf] = (f32x4)0.0f;
        #pragma unroll
        for (int r = 0; r < 4; ++r) { mst[mf][r] = -__builtin_inff(); lst[mf][r] = 0.0f; }
    }

    const int kvend = qt*128 + 128;
    for (int kv = 0; kv < kvend; kv += 64) {
        __syncthreads();
        {   // stage K (row-major) and V^T
            const int r = t >> 2;
            const int c = (t & 3) << 4;
            *(i32x4*)(&Kl[r][c])     = *(const i32x4*)(K + (size_t)(kv + r)*D_HD + c);
            *(i32x4*)(&Kl[r][c + 8]) = *(const i32x4*)(K + (size_t)(kv + r)*D_HD + c + 8);
            const unsigned short* vp = V + (size_t)(kv + r)*D_HD + c;
            #pragma unroll
            for (int j = 0; j < 16; ++j) Vt[c + j][r] = vp[j];
        }
        __syncthreads();

        if (kv <= qbase + 31) {
            // S = Q K^T
            f32x4 sa[2][4];
            #pragma unroll
            for (int mf = 0; mf < 2; ++mf)
                #pragma unroll
                for (int nf = 0; nf < 4; ++nf) sa[mf][nf] = (f32x4)0.0f;
            #pragma unroll
            for (int ks = 0; ks < 2; ++ks)
                #pragma unroll
                for (int nf = 0; nf < 4; ++nf) {
                    bf16x8 kf = *(const bf16x8*)(&Kl[nf*16 + lrow][ks*32 + lk*8]);
                    #pragma unroll
                    for (int mf = 0; mf < 2; ++mf)
                        sa[mf][nf] = MFMA(qf[mf][ks], kf, sa[mf][nf]);
                }
            const bool need_mask = (kv + 63 > qbase);
            #pragma unroll
            for (int mf = 0; mf < 2; ++mf)
                #pragma unroll
                for (int nf = 0; nf < 4; ++nf)
                    #pragma unroll
                    for (int r = 0; r < 4; ++r) {
                        float sv = sa[mf][nf][r] * 0.125f;
                        if (need_mask) {
                            const int row = qbase + mf*16 + lk*4 + r;
                            const int col = kv + nf*16 + lrow;
                            if (col > row) sv = -__builtin_inff();
                        }
                        sa[mf][nf][r] = sv;
                    }
            // online softmax (rows live on (lk,reg); cols on lrow -> 16-lane reduce)
            #pragma unroll
            for (int mf = 0; mf < 2; ++mf) {
                #pragma unroll
                for (int r = 0; r < 4; ++r) {
                    float mx = fmaxf(fmaxf(sa[mf][0][r], sa[mf][1][r]),
                                     fmaxf(sa[mf][2][r], sa[mf][3][r]));
                    mx = fmaxf(mx, __shfl_xor(mx, 1));
                    mx = fmaxf(mx, __shfl_xor(mx, 2));
                    mx = fmaxf(mx, __shfl_xor(mx, 4));
                    mx = fmaxf(mx, __shfl_xor(mx, 8));
                    const float mnew  = fmaxf(mst[mf][r], mx);
                    const float alpha = __expf(mst[mf][r] - mnew);
                    mst[mf][r] = mnew;
                    float sum = 0.0f;
                    #pragma unroll
                    for (int nf = 0; nf < 4; ++nf) {
                        float p = __expf(sa[mf][nf][r] - mnew);
                        sa[mf][nf][r] = p;
                        sum += p;
                    }
                    sum += __shfl_xor(sum, 1);
                    sum += __shfl_xor(sum, 2);
                    sum += __shfl_xor(sum, 4);
                    sum += __shfl_xor(sum, 8);
                    lst[mf][r] = lst[mf][r] * alpha + sum;
                    #pragma unroll
                    for (int nf = 0; nf < 4; ++nf)
                        ctxa[mf][nf][r] *= alpha;
                }
            }
            // P -> LDS (per-wave buffer; same-wave DS ordering, no barrier needed)
            #pragma unroll
            for (int mf = 0; mf < 2; ++mf)
                #pragma unroll
                for (int nf = 0; nf < 4; ++nf)
                    #pragma unroll
                    for (int r = 0; r < 4; ++r)
                        Pl[wave][mf*16 + lk*4 + r][nf*16 + lrow] = f2bf(sa[mf][nf][r]);
            // ctx += P V
            #pragma unroll
            for (int ks = 0; ks < 2; ++ks) {
                bf16x8 pa[2];
                #pragma unroll
                for (int mf = 0; mf < 2; ++mf)
                    pa[mf] = *(const bf16x8*)(&Pl[wave][mf*16 + lrow][ks*32 + lk*8]);
                #pragma unroll
                for (int nf = 0; nf < 4; ++nf) {
                    bf16x8 vf = *(const bf16x8*)(&Vt[nf*16 + lrow][ks*32 + lk*8]);
                    #pragma unroll
                    for (int mf = 0; mf < 2; ++mf)
                        ctxa[mf][nf] = MFMA(pa[mf], vf, ctxa[mf][nf]);
                }
            }
        }
    }

    // epilogue: normalize, write ctx bf16 [S,B,E]; write m,l
    #pragma unroll
    for (int mf = 0; mf < 2; ++mf) {
        #pragma unroll
        for (int r = 0; r < 4; ++r) {
            const float inv = 1.0f / lst[mf][r];
            const int srow = qbase + mf*16 + lk*4 + r;
            #pragma unroll
            for (int nf = 0; nf < 4; ++nf) {
                const int d = nf*16 + lrow;
                ctx[((size_t)srow * B_SZ + b) * E_SZ + h*D_HD + d] = f2bf(ctxa[mf][nf][r] * inv);
            }
            if (lrow == 0) {
                mout[(size_t)bh * S_LEN + srow] = mst[mf][r];
                lout[(size_t)bh * S_LEN + srow] = lst[mf][r];
            }
        }
    }
}

// ---------------- attn_map: mean over heads of probs ----------------
// grid: B * 32 * 32 (64x64 output tiles); recompute QK^T, use stored m,l
__global__ __launch_bounds__(256)
void attn_map_k(const unsigned short* __restrict__ Qb,
                const unsigned short* __restrict__ Kb,
                const float* __restrict__ mrows,
                const float* __restrict__ lrows,
                float* __restrict__ map)
{
    const int t  = threadIdx.x;
    const int jt = blockIdx.x & 31;
    const int it = (blockIdx.x >> 5) & 31;
    const int b  = blockIdx.x >> 10;
    float* mt = map + ((size_t)b * S_LEN + it*64) * S_LEN + jt*64;

    if (jt > it) {   // fully-masked tile: write zeros
        const int r = t >> 2;
        const int c = (t & 3) << 4;
        f32x4 z = (f32x4)0.0f;
        #pragma unroll
        for (int j = 0; j < 4; ++j)
            *(f32x4*)(mt + (size_t)r * S_LEN + c + j*4) = z;
        return;
    }

    __shared__ unsigned short Ql[64][72];
    __shared__ unsigned short Kl[64][72];

    const int lane = t & 63, wave = t >> 6;
    const int lrow = lane & 15, lk = lane >> 4;

    f32x4 pacc[4];
    #pragma unroll
    for (int nf = 0; nf < 4; ++nf) pacc[nf] = (f32x4)0.0f;

    for (int h = 0; h < H_CNT; ++h) {
        const size_t base = (size_t)(b*H_CNT + h) * S_LEN * D_HD;
        __syncthreads();
        {
            const int r = t >> 2;
            const int c = (t & 3) << 4;
            const unsigned short* qp = Qb + base + (size_t)(it*64 + r)*D_HD + c;
            const unsigned short* kp = Kb + base + (size_t)(jt*64 + r)*D_HD + c;
            *(i32x4*)(&Ql[r][c])     = *(const i32x4*)qp;
            *(i32x4*)(&Ql[r][c + 8]) = *(const i32x4*)(qp + 8);
            *(i32x4*)(&Kl[r][c])     = *(const i32x4*)kp;
            *(i32x4*)(&Kl[r][c + 8]) = *(const i32x4*)(kp + 8);
        }
        __syncthreads();

        f32x4 sa[4];
        #pragma unroll
        for (int nf = 0; nf < 4; ++nf) sa[nf] = (f32x4)0.0f;
        #pragma unroll
        for (int ks = 0; ks < 2; ++ks) {
            bf16x8 qa = *(const bf16x8*)(&Ql[wave*16 + lrow][ks*32 + lk*8]);
            #pragma unroll
            for (int nf = 0; nf < 4; ++nf) {
                bf16x8 kf = *(const bf16x8*)(&Kl[nf*16 + lrow][ks*32 + lk*8]);
                sa[nf] = MFMA(qa, kf, sa[nf]);
            }
        }
        const int rowbase = it*64 + wave*16 + lk*4;
        #pragma unroll
        for (int r = 0; r < 4; ++r) {
            const float mv = mrows[(size_t)(b*H_CNT + h)*S_LEN + rowbase + r];
            const float lv = 1.0f / lrows[(size_t)(b*H_CNT + h)*S_LEN + rowbase + r];
            #pragma unroll
            for (int nf = 0; nf < 4; ++nf)
                pacc[nf][r] += __expf(sa[nf][r]*0.125f - mv) * lv;
        }
    }

    const float sc = 1.0f / (float)H_CNT;
    #pragma unroll
    for (int nf = 0; nf < 4; ++nf)
        #pragma unroll
        for (int r = 0; r < 4; ++r) {
            const int row = wave*16 + lk*4 + r;
            const int col = nf*16 + lrow;
            float v = pacc[nf][r] * sc;
            if (it == jt && col > row) v = 0.0f;   // diagonal-tile causal mask
            mt[(size_t)row * S_LEN + col] = v;
        }
}

// ---------------- launch ----------------
extern "C" void kernel_launch(void* const* d_in, const int* in_sizes, int n_in,
                              void* d_out, int out_size, void* d_ws, size_t ws_size,
                              hipStream_t stream)
{
    const float* q_in = (const float*)d_in[0];
    const float* k_in = (const float*)d_in[1];
    const float* v_in = (const float*)d_in[2];
    // d_in[3]: attn_mask — known causal triu(k=1), applied analytically
    const float* Wq = (const float*)d_in[4];
    const float* bq = (const float*)d_in[5];
    const float* Wk = (const float*)d_in[6];
    const float* bk = (const float*)d_in[7];
    const float* Wv = (const float*)d_in[8];
    const float* bv = (const float*)d_in[9];
    const float* Wo = (const float*)d_in[10];
    const float* bo = (const float*)d_in[11];

    const size_t EE   = (size_t)E_SZ * E_SZ;           // 1M elems
    const size_t BHSD = (size_t)B_SZ * H_CNT * S_LEN * D_HD;  // 8.39M elems
    const size_t SBE  = (size_t)S_LEN * B_SZ * E_SZ;   // 8.39M elems

    unsigned short* Wqb = (unsigned short*)d_ws;
    unsigned short* Wkb = Wqb + EE;
    unsigned short* Wvb = Wkb + EE;
    unsigned short* Wob = Wvb + EE;
    unsigned short* Qb  = Wob + EE;
    unsigned short* Kb  = Qb + BHSD;
    unsigned short* Vb  = Kb + BHSD;
    unsigned short* ctx = Vb + BHSD;
    float* mrows = (float*)(ctx + SBE);
    float* lrows = mrows + (size_t)B_SZ * H_CNT * S_LEN;

    float* out = (float*)d_out;
    float* map = out + SBE;

    const int n4 = (int)(EE / 4);
    convert_f32_bf16<<<n4/256, 256, 0, stream>>>(Wq, Wqb, n4);
    convert_f32_bf16<<<n4/256, 256, 0, stream>>>(Wk, Wkb, n4);
    convert_f32_bf16<<<n4/256, 256, 0, stream>>>(Wv, Wvb, n4);
    convert_f32_bf16<<<n4/256, 256, 0, stream>>>(Wo, Wob, n4);

    proj_gemm<true, true><<<512, 256, 0, stream>>>(q_in, Wqb, bq, Qb);
    proj_gemm<true, true><<<512, 256, 0, stream>>>(k_in, Wkb, bk, Kb);
    proj_gemm<true, true><<<512, 256, 0, stream>>>(v_in, Wvb, bv, Vb);

    flash_fwd<<<B_SZ*H_CNT*(S_LEN/128), 256, 0, stream>>>(Qb, Kb, Vb, ctx, mrows, lrows);

    proj_gemm<false, false><<<512, 256, 0, stream>>>(ctx, Wob, bo, d_out);

    attn_map_k<<<B_SZ*32*32, 256, 0, stream>>>(Qb, Kb, mrows, lrows, map);
}

// Round 2
// 374.395 us; speedup vs baseline: 1.4278x; 1.4278x over previous
//
#include <hip/hip_runtime.h>
#include <stdint.h>

#define S_LEN 2048
#define B_SZ  4
#define E_SZ  1024
#define H_CNT 16
#define D_HD  64

typedef __attribute__((ext_vector_type(4))) float          f32x4;
typedef __attribute__((ext_vector_type(8))) __bf16         bf16x8;
typedef __attribute__((ext_vector_type(4))) unsigned short u16x4;
typedef __attribute__((ext_vector_type(4))) int            i32x4;

__device__ __forceinline__ unsigned short f2bf(float f) {
    union { float f; unsigned u; } v; v.f = f;
    unsigned r = v.u + 0x7fffu + ((v.u >> 16) & 1u);
    return (unsigned short)(r >> 16);
}

#define MFMA(a, b, c) __builtin_amdgcn_mfma_f32_16x16x32_bf16((a), (b), (c), 0, 0, 0)

__device__ __forceinline__ void gll16(const void* g, void* l) {
    __builtin_amdgcn_global_load_lds(
        (const __attribute__((address_space(1))) void*)g,
        (__attribute__((address_space(3))) void*)l, 16, 0, 0);
}

// ---------------- fp32 -> bf16 conversion (up to 4 arrays via gridDim.y) ----------------
__global__ __launch_bounds__(256)
void convert_many(const float* __restrict__ s0, const float* __restrict__ s1,
                  const float* __restrict__ s2, const float* __restrict__ s3,
                  unsigned short* __restrict__ d0, unsigned short* __restrict__ d1,
                  unsigned short* __restrict__ d2, unsigned short* __restrict__ d3,
                  float sc0)
{
    const int which = blockIdx.y;
    const float* s = which == 0 ? s0 : which == 1 ? s1 : which == 2 ? s2 : s3;
    unsigned short* d = which == 0 ? d0 : which == 1 ? d1 : which == 2 ? d2 : d3;
    const float sc = which == 0 ? sc0 : 1.0f;
    const int i = blockIdx.x * 256 + threadIdx.x;
    f32x4 v = ((const f32x4*)s)[i];
    u16x4 o;
    o.x = f2bf(v.x * sc); o.y = f2bf(v.y * sc);
    o.z = f2bf(v.z * sc); o.w = f2bf(v.w * sc);
    ((u16x4*)d)[i] = o;
}

// ---------------- GEMM: C = A * W^T + b  (m97 structure, BK=64, linear LDS) ----------------
// A: [8192,1024] (bf16, or fp32 reg-staged when AF32)
// W: [1024,1024] bf16 row-major (K contiguous)
template<bool AF32, bool OUT_QKV>
__global__ __launch_bounds__(256)
void gemm_bt(const void* __restrict__ Ap,
             const unsigned short* __restrict__ Bw,
             const float* __restrict__ bias, float bscale,
             void* __restrict__ Outp)
{
    __shared__ unsigned short Al[128 * 64];
    __shared__ unsigned short Bl[128 * 64];

    const int t    = threadIdx.x;
    const int lane = t & 63;
    const int wave = t >> 6;
    const int lrow = lane & 15;
    const int lk   = lane >> 4;
    const int bm   = (blockIdx.x >> 3) << 7;
    const int bn   = (blockIdx.x & 7) << 7;
    const int wr   = (wave >> 1) << 6;
    const int wc   = (wave & 1) << 6;

    f32x4 acc[4][4];
    #pragma unroll
    for (int i = 0; i < 4; ++i)
        #pragma unroll
        for (int j = 0; j < 4; ++j) acc[i][j] = (f32x4)0.0f;

    for (int k0 = 0; k0 < E_SZ; k0 += 64) {
        __syncthreads();
        #pragma unroll
        for (int j = 0; j < 4; ++j) {
            const int chunk = wave * 4 + j;                // 16 chunks of 8 rows
            const int r = chunk * 8 + (lane >> 3);
            const int c = (lane & 7) << 3;
            if (AF32) {
                const float* ga = (const float*)Ap + (size_t)(bm + r) * E_SZ + k0 + c;
                f32x4 u0 = *(const f32x4*)ga;
                f32x4 u1 = *(const f32x4*)(ga + 4);
                unsigned w0 = (unsigned)f2bf(u0.x) | ((unsigned)f2bf(u0.y) << 16);
                unsigned w1 = (unsigned)f2bf(u0.z) | ((unsigned)f2bf(u0.w) << 16);
                unsigned w2 = (unsigned)f2bf(u1.x) | ((unsigned)f2bf(u1.y) << 16);
                unsigned w3 = (unsigned)f2bf(u1.z) | ((unsigned)f2bf(u1.w) << 16);
                i32x4 wv; wv.x = (int)w0; wv.y = (int)w1; wv.z = (int)w2; wv.w = (int)w3;
                *(i32x4*)(&Al[chunk * 512 + lane * 8]) = wv;
            } else {
                const unsigned short* ga = (const unsigned short*)Ap + (size_t)(bm + r) * E_SZ + k0 + c;
                gll16(ga, &Al[chunk * 512]);
            }
            const unsigned short* gb = Bw + (size_t)(bn + r) * E_SZ + k0 + c;
            gll16(gb, &Bl[chunk * 512]);
        }
        __syncthreads();
        #pragma unroll
        for (int kk = 0; kk < 2; ++kk) {
            bf16x8 af[4], bfr[4];
            #pragma unroll
            for (int i = 0; i < 4; ++i)
                af[i] = *(const bf16x8*)(&Al[(wr + i*16 + lrow) * 64 + kk*32 + lk*8]);
            #pragma unroll
            for (int j = 0; j < 4; ++j)
                bfr[j] = *(const bf16x8*)(&Bl[(wc + j*16 + lrow) * 64 + kk*32 + lk*8]);
            #pragma unroll
            for (int i = 0; i < 4; ++i)
                #pragma unroll
                for (int j = 0; j < 4; ++j)
                    acc[i][j] = MFMA(af[i], bfr[j], acc[i][j]);
        }
    }

    const int crow = lk << 2;
    #pragma unroll
    for (int i = 0; i < 4; ++i) {
        #pragma unroll
        for (int j = 0; j < 4; ++j) {
            const int n = bn + wc + j*16 + lrow;
            const float bv = bias[n] * bscale;
            #pragma unroll
            for (int r = 0; r < 4; ++r) {
                const int m = bm + wr + i*16 + crow + r;
                const float val = acc[i][j][r] + bv;
                if (OUT_QKV) {
                    const int s = m >> 2, b = m & 3;       // m = s*B + b
                    const int h = n >> 6, d = n & 63;      // n = h*D + d
                    ((unsigned short*)Outp)[((size_t)(b*H_CNT + h)*S_LEN + s)*D_HD + d] = f2bf(val);
                } else {
                    ((float*)Outp)[(size_t)m * E_SZ + n] = val;
                }
            }
        }
    }
}

// ---------------- flash attention fwd (causal), balanced pairing ----------------
// grid: B*H*8 = 512; block 256. Each block does q-tiles (15-pt) and pt -> 17 kv-tiles.
// Q is PRE-SCALED by 1/8 (folded into Wq/bq).
__global__ __launch_bounds__(256)
void flash_fwd(const unsigned short* __restrict__ Qb,
               const unsigned short* __restrict__ Kb,
               const unsigned short* __restrict__ Vb,
               unsigned short* __restrict__ ctx,
               float* __restrict__ mout,
               float* __restrict__ lout)
{
    __shared__ unsigned short Kl[64][72];
    __shared__ unsigned short Vt[64][72];   // V transposed: [d][kv]
    __shared__ unsigned short Pl[4][32][72];

    const int t    = threadIdx.x;
    const int lane = t & 63, wave = t >> 6;
    const int lrow = lane & 15, lk = lane >> 4;
    const int pt   = blockIdx.x & 7;
    const int bh   = blockIdx.x >> 3;
    const int b    = bh >> 4, h = bh & 15;

    const size_t base = (size_t)bh * S_LEN * D_HD;
    const unsigned short* Q = Qb + base;
    const unsigned short* K = Kb + base;
    const unsigned short* V = Vb + base;

    const int vp2 = (t & 31) << 1;   // kv pair base for V^T staging
    const int vd8 = (t >> 5) << 3;   // d base (0..56)
    const int kr  = t >> 2;          // K staging row
    const int kc  = (t & 3) << 4;    // K staging col

    for (int phase = 0; phase < 2; ++phase) {
        const int qt    = phase ? pt : (15 - pt);
        const int qbase = qt * 128 + wave * 32;

        bf16x8 qf[2][2];
        #pragma unroll
        for (int mf = 0; mf < 2; ++mf)
            #pragma unroll
            for (int ks = 0; ks < 2; ++ks)
                qf[mf][ks] = *(const bf16x8*)(Q + (size_t)(qbase + mf*16 + lrow)*D_HD + ks*32 + lk*8);

        f32x4 ctxa[2][4];
        float mst[2][4], lst[2][4];
        #pragma unroll
        for (int mf = 0; mf < 2; ++mf) {
            #pragma unroll
            for (int nf = 0; nf < 4; ++nf) ctxa[mf][nf] = (f32x4)0.0f;
            #pragma unroll
            for (int r = 0; r < 4; ++r) { mst[mf][r] = -__builtin_inff(); lst[mf][r] = 0.0f; }
        }

        const int kvend = qt*128 + 128;
        for (int kv = 0; kv < kvend; kv += 64) {
            __syncthreads();
            {   // stage K row-major (b128 x2) and V^T (2x b128 load + 8x b32 write)
                *(i32x4*)(&Kl[kr][kc])   = *(const i32x4*)(K + (size_t)(kv + kr)*D_HD + kc);
                *(i32x4*)(&Kl[kr][kc+8]) = *(const i32x4*)(K + (size_t)(kv + kr)*D_HD + kc + 8);
                const unsigned short* vp = V + (size_t)(kv + vp2)*D_HD + vd8;
                i32x4 v0 = *(const i32x4*)vp;
                i32x4 v1 = *(const i32x4*)(vp + D_HD);
                union { i32x4 v; unsigned short s[8]; } ua, ub;
                ua.v = v0; ub.v = v1;
                #pragma unroll
                for (int j = 0; j < 8; ++j) {
                    unsigned w = (unsigned)ua.s[j] | ((unsigned)ub.s[j] << 16);
                    *(unsigned*)(&Vt[vd8 + j][vp2]) = w;
                }
            }
            __syncthreads();

            if (kv <= qbase + 31) {
                // S = Q K^T (Q pre-scaled by 1/8)
                f32x4 sa[2][4];
                #pragma unroll
                for (int mf = 0; mf < 2; ++mf)
                    #pragma unroll
                    for (int nf = 0; nf < 4; ++nf) sa[mf][nf] = (f32x4)0.0f;
                #pragma unroll
                for (int ks = 0; ks < 2; ++ks)
                    #pragma unroll
                    for (int nf = 0; nf < 4; ++nf) {
                        bf16x8 kf = *(const bf16x8*)(&Kl[nf*16 + lrow][ks*32 + lk*8]);
                        #pragma unroll
                        for (int mf = 0; mf < 2; ++mf)
                            sa[mf][nf] = MFMA(qf[mf][ks], kf, sa[mf][nf]);
                    }
                const bool need_mask = (kv + 63 > qbase);
                if (need_mask) {
                    #pragma unroll
                    for (int mf = 0; mf < 2; ++mf)
                        #pragma unroll
                        for (int nf = 0; nf < 4; ++nf)
                            #pragma unroll
                            for (int r = 0; r < 4; ++r) {
                                const int row = qbase + mf*16 + lk*4 + r;
                                const int col = kv + nf*16 + lrow;
                                if (col > row) sa[mf][nf][r] = -__builtin_inff();
                            }
                }
                // online softmax
                #pragma unroll
                for (int mf = 0; mf < 2; ++mf) {
                    #pragma unroll
                    for (int r = 0; r < 4; ++r) {
                        float mx = fmaxf(fmaxf(sa[mf][0][r], sa[mf][1][r]),
                                         fmaxf(sa[mf][2][r], sa[mf][3][r]));
                        mx = fmaxf(mx, __shfl_xor(mx, 1));
                        mx = fmaxf(mx, __shfl_xor(mx, 2));
                        mx = fmaxf(mx, __shfl_xor(mx, 4));
                        mx = fmaxf(mx, __shfl_xor(mx, 8));
                        const float mnew  = fmaxf(mst[mf][r], mx);
                        const float alpha = __expf(mst[mf][r] - mnew);
                        mst[mf][r] = mnew;
                        float sum = 0.0f;
                        #pragma unroll
                        for (int nf = 0; nf < 4; ++nf) {
                            float p = __expf(sa[mf][nf][r] - mnew);
                            sa[mf][nf][r] = p;
                            sum += p;
                        }
                        sum += __shfl_xor(sum, 1);
                        sum += __shfl_xor(sum, 2);
                        sum += __shfl_xor(sum, 4);
                        sum += __shfl_xor(sum, 8);
                        lst[mf][r] = lst[mf][r] * alpha + sum;
                        #pragma unroll
                        for (int nf = 0; nf < 4; ++nf)
                            ctxa[mf][nf][r] *= alpha;
                    }
                }
                // P -> LDS (per-wave buffer; same-wave DS ordering)
                #pragma unroll
                for (int mf = 0; mf < 2; ++mf)
                    #pragma unroll
                    for (int nf = 0; nf < 4; ++nf)
                        #pragma unroll
                        for (int r = 0; r < 4; ++r)
                            Pl[wave][mf*16 + lk*4 + r][nf*16 + lrow] = f2bf(sa[mf][nf][r]);
                // ctx += P V
                #pragma unroll
                for (int ks = 0; ks < 2; ++ks) {
                    bf16x8 pa[2];
                    #pragma unroll
                    for (int mf = 0; mf < 2; ++mf)
                        pa[mf] = *(const bf16x8*)(&Pl[wave][mf*16 + lrow][ks*32 + lk*8]);
                    #pragma unroll
                    for (int nf = 0; nf < 4; ++nf) {
                        bf16x8 vf = *(const bf16x8*)(&Vt[nf*16 + lrow][ks*32 + lk*8]);
                        #pragma unroll
                        for (int mf = 0; mf < 2; ++mf)
                            ctxa[mf][nf] = MFMA(pa[mf], vf, ctxa[mf][nf]);
                    }
                }
            }
        }

        // epilogue: normalize, write ctx bf16 [S,B,E]; write m,l
        #pragma unroll
        for (int mf = 0; mf < 2; ++mf) {
            #pragma unroll
            for (int r = 0; r < 4; ++r) {
                const float inv = 1.0f / lst[mf][r];
                const int srow = qbase + mf*16 + lk*4 + r;
                #pragma unroll
                for (int nf = 0; nf < 4; ++nf) {
                    const int d = nf*16 + lrow;
                    ctx[((size_t)srow * B_SZ + b) * E_SZ + h*D_HD + d] = f2bf(ctxa[mf][nf][r] * inv);
                }
                if (lrow == 0) {
                    mout[(size_t)bh * S_LEN + srow] = mst[mf][r];
                    lout[(size_t)bh * S_LEN + srow] = lst[mf][r];
                }
            }
        }
    }
}

// ---------------- attn_map: mean over heads of probs ----------------
__global__ __launch_bounds__(256)
void attn_map_k(const unsigned short* __restrict__ Qb,
                const unsigned short* __restrict__ Kb,
                const float* __restrict__ mrows,
                const float* __restrict__ lrows,
                float* __restrict__ map)
{
    const int t  = threadIdx.x;
    const int jt = blockIdx.x & 31;
    const int it = (blockIdx.x >> 5) & 31;
    const int b  = blockIdx.x >> 10;
    float* mt = map + ((size_t)b * S_LEN + it*64) * S_LEN + jt*64;

    if (jt > it) {   // fully-masked tile: zeros
        const int r = t >> 2;
        const int c = (t & 3) << 4;
        f32x4 z = (f32x4)0.0f;
        #pragma unroll
        for (int j = 0; j < 4; ++j)
            *(f32x4*)(mt + (size_t)r * S_LEN + c + j*4) = z;
        return;
    }

    __shared__ unsigned short Ql[64][72];
    __shared__ unsigned short Kl[64][72];

    const int lane = t & 63, wave = t >> 6;
    const int lrow = lane & 15, lk = lane >> 4;

    f32x4 pacc[4];
    #pragma unroll
    for (int nf = 0; nf < 4; ++nf) pacc[nf] = (f32x4)0.0f;

    for (int h = 0; h < H_CNT; ++h) {
        const size_t base = (size_t)(b*H_CNT + h) * S_LEN * D_HD;
        __syncthreads();
        {
            const int r = t >> 2;
            const int c = (t & 3) << 4;
            const unsigned short* qp = Qb + base + (size_t)(it*64 + r)*D_HD + c;
            const unsigned short* kp = Kb + base + (size_t)(jt*64 + r)*D_HD + c;
            *(i32x4*)(&Ql[r][c])     = *(const i32x4*)qp;
            *(i32x4*)(&Ql[r][c + 8]) = *(const i32x4*)(qp + 8);
            *(i32x4*)(&Kl[r][c])     = *(const i32x4*)kp;
            *(i32x4*)(&Kl[r][c + 8]) = *(const i32x4*)(kp + 8);
        }
        __syncthreads();

        f32x4 sa[4];
        #pragma unroll
        for (int nf = 0; nf < 4; ++nf) sa[nf] = (f32x4)0.0f;
        #pragma unroll
        for (int ks = 0; ks < 2; ++ks) {
            bf16x8 qa = *(const bf16x8*)(&Ql[wave*16 + lrow][ks*32 + lk*8]);
            #pragma unroll
            for (int nf = 0; nf < 4; ++nf) {
                bf16x8 kf = *(const bf16x8*)(&Kl[nf*16 + lrow][ks*32 + lk*8]);
                sa[nf] = MFMA(qa, kf, sa[nf]);
            }
        }
        const int rowbase = it*64 + wave*16 + lk*4;
        #pragma unroll
        for (int r = 0; r < 4; ++r) {
            const float mv = mrows[(size_t)(b*H_CNT + h)*S_LEN + rowbase + r];
            const float lv = 1.0f / lrows[(size_t)(b*H_CNT + h)*S_LEN + rowbase + r];
            #pragma unroll
            for (int nf = 0; nf < 4; ++nf)
                pacc[nf][r] += __expf(sa[nf][r] - mv) * lv;
        }
    }

    const float sc = 1.0f / (float)H_CNT;
    #pragma unroll
    for (int nf = 0; nf < 4; ++nf)
        #pragma unroll
        for (int r = 0; r < 4; ++r) {
            const int row = wave*16 + lk*4 + r;
            const int col = nf*16 + lrow;
            float v = pacc[nf][r] * sc;
            if (it == jt && col > row) v = 0.0f;
            mt[(size_t)row * S_LEN + col] = v;
        }
}

// ---------------- launch ----------------
extern "C" void kernel_launch(void* const* d_in, const int* in_sizes, int n_in,
                              void* d_out, int out_size, void* d_ws, size_t ws_size,
                              hipStream_t stream)
{
    const float* q_in = (const float*)d_in[0];
    const float* k_in = (const float*)d_in[1];
    const float* v_in = (const float*)d_in[2];
    // d_in[3]: attn_mask — known causal triu(k=1), applied analytically
    const float* Wq = (const float*)d_in[4];
    const float* bq = (const float*)d_in[5];
    const float* Wk = (const float*)d_in[6];
    const float* bk = (const float*)d_in[7];
    const float* Wv = (const float*)d_in[8];
    const float* bv = (const float*)d_in[9];
    const float* Wo = (const float*)d_in[10];
    const float* bo = (const float*)d_in[11];

    const size_t EE   = (size_t)E_SZ * E_SZ;                  // 1,048,576
    const size_t BHSD = (size_t)B_SZ * H_CNT * S_LEN * D_HD;  // 8,388,608
    const size_t SBE  = (size_t)S_LEN * B_SZ * E_SZ;          // 8,388,608

    unsigned short* Wqb = (unsigned short*)d_ws;
    unsigned short* Wkb = Wqb + EE;
    unsigned short* Wvb = Wkb + EE;
    unsigned short* Wob = Wvb + EE;
    unsigned short* base = Wob + EE;

    const size_t need_big = (4*EE + 6*BHSD) * sizeof(unsigned short);  // ~109 MB
    const bool big = ws_size >= need_big;

    unsigned short *Aq, *Ak, *Av, *Qb, *Kb, *Vb, *ctx;
    float* ml;
    if (big) {
        Aq = base;       Ak = Aq + BHSD;  Av = Ak + BHSD;
        Qb = Av + BHSD;  Kb = Qb + BHSD;  Vb = Kb + BHSD;
        ctx = Aq;                 // Aq dead after Q-projection
        ml  = (float*)Ak;         // Ak dead after K-projection
    } else {
        Aq = Ak = Av = nullptr;
        Qb = base;       Kb = Qb + BHSD;  Vb = Kb + BHSD;
        ctx = Vb + BHSD;
        ml  = (float*)(ctx + SBE);
    }
    float* mrows = ml;
    float* lrows = ml + (size_t)B_SZ * H_CNT * S_LEN;

    float* out = (float*)d_out;
    float* map = out + SBE;

    // weights (Wq scaled by 1/8: exact exponent shift, folds softmax scale)
    convert_many<<<dim3(1024, 4), 256, 0, stream>>>(Wq, Wk, Wv, Wo, Wqb, Wkb, Wvb, Wob, 0.125f);

    if (big) {
        convert_many<<<dim3(8192, 3), 256, 0, stream>>>(q_in, k_in, v_in, nullptr,
                                                        Aq, Ak, Av, nullptr, 1.0f);
        gemm_bt<false, true><<<512, 256, 0, stream>>>(Aq, Wqb, bq, 0.125f, Qb);
        gemm_bt<false, true><<<512, 256, 0, stream>>>(Ak, Wkb, bk, 1.0f,   Kb);
        gemm_bt<false, true><<<512, 256, 0, stream>>>(Av, Wvb, bv, 1.0f,   Vb);
    } else {
        gemm_bt<true, true><<<512, 256, 0, stream>>>(q_in, Wqb, bq, 0.125f, Qb);
        gemm_bt<true, true><<<512, 256, 0, stream>>>(k_in, Wkb, bk, 1.0f,   Kb);
        gemm_bt<true, true><<<512, 256, 0, stream>>>(v_in, Wvb, bv, 1.0f,   Vb);
    }

    flash_fwd<<<B_SZ*H_CNT*8, 256, 0, stream>>>(Qb, Kb, Vb, ctx, mrows, lrows);

    gemm_bt<false, false><<<512, 256, 0, stream>>>(ctx, Wob, bo, 1.0f, d_out);

    attn_map_k<<<B_SZ*32*32, 256, 0, stream>>>(Qb, Kb, mrows, lrows, map);
}